// Round 3
// 1366.420 us; speedup vs baseline: 1.2030x; 1.2030x over previous
//
#include <hip/hip_runtime.h>

static constexpr int kT = 8192;
static constexpr int kH = 2048;
static constexpr int kI = 1408;
static constexpr int kE = 16;

typedef __bf16 bf16x8 __attribute__((ext_vector_type(8)));
typedef float floatx4 __attribute__((ext_vector_type(4)));

__device__ __forceinline__ __bf16 f2bf(float f) { return (__bf16)f; }

__device__ __forceinline__ uint4 pack8(float4 a, float4 b) {
    union { __bf16 h[8]; uint4 u; } o;
    o.h[0] = f2bf(a.x); o.h[1] = f2bf(a.y); o.h[2] = f2bf(a.z); o.h[3] = f2bf(a.w);
    o.h[4] = f2bf(b.x); o.h[5] = f2bf(b.y); o.h[6] = f2bf(b.z); o.h[7] = f2bf(b.w);
    return o.u;
}

// ---------------- x fp32 -> bf16 (8 elems/thread) ----------------
__global__ void cvt_x_kernel(const float* __restrict__ x, __bf16* __restrict__ xb) {
    size_t i = ((size_t)blockIdx.x * 256 + threadIdx.x) * 8;
    float4 v0 = *(const float4*)(x + i);
    float4 v1 = *(const float4*)(x + i + 4);
    *(uint4*)(xb + i) = pack8(v0, v1);
}

// ---------------- gating: fp32 logits, top-2, softmax ----------------
__global__ __launch_bounds__(256)
void gate_kernel(const float* __restrict__ x, const float* __restrict__ gw,
                 int* __restrict__ t_ids, float* __restrict__ t_w,
                 int* __restrict__ counts) {
    const int lane = threadIdx.x & 63;
    const int t = blockIdx.x * 4 + (threadIdx.x >> 6);
    float acc[kE];
#pragma unroll
    for (int e = 0; e < kE; ++e) acc[e] = 0.f;
    const float* xr = x + (size_t)t * kH;
    for (int h = lane; h < kH; h += 64) {
        const float xv = xr[h];
#pragma unroll
        for (int e = 0; e < kE; ++e) acc[e] += xv * gw[e * kH + h];
    }
#pragma unroll
    for (int e = 0; e < kE; ++e) {
        float v = acc[e];
        for (int off = 32; off > 0; off >>= 1) v += __shfl_xor(v, off, 64);
        acc[e] = v;
    }
    if (lane == 0) {
        int i0 = 0; float l0 = acc[0];
#pragma unroll
        for (int e = 1; e < kE; ++e) if (acc[e] > l0) { l0 = acc[e]; i0 = e; }
        int i1 = -1; float l1 = -3.4e38f;
#pragma unroll
        for (int e = 0; e < kE; ++e) if (e != i0 && acc[e] > l1) { l1 = acc[e]; i1 = e; }
        const float ex = __expf(l1 - l0);
        const float inv = 1.f / (1.f + ex);
        t_ids[2 * t] = i0; t_ids[2 * t + 1] = i1;
        t_w[2 * t] = inv;  t_w[2 * t + 1] = ex * inv;
        atomicAdd(counts + i0, 1);
        atomicAdd(counts + i1, 1);
    }
}

// ---------------- tiny exclusive scan over 16 counts ----------------
__global__ void scan_kernel(const int* __restrict__ counts, int* __restrict__ offs,
                            int* __restrict__ fill) {
    if (threadIdx.x == 0) {
        int s = 0;
        for (int e = 0; e < kE; ++e) { offs[e] = s; fill[e] = s; s += counts[e]; }
        offs[kE] = s;
    }
}

// ---------------- scatter token ids into expert buckets ----------------
__global__ void scatter_kernel(const int* __restrict__ t_ids, const float* __restrict__ t_w,
                               int* __restrict__ fill, int* __restrict__ btok,
                               float* __restrict__ bw) {
    int t = blockIdx.x * 256 + threadIdx.x;
    if (t < kT) {
#pragma unroll
        for (int k = 0; k < 2; ++k) {
            int e = t_ids[2 * t + k];
            int pos = atomicAdd(fill + e, 1);
            btok[pos] = t;
            bw[pos] = t_w[2 * t + k];
        }
    }
}

// ---------------- grouped GEMM1: h = silu(Xe@W1^T)*(Xe@Up^T)*w ----------------
// BM=128, BN=64(x2 mats), BK=64. Double-buffered LDS, 1 barrier/K-step.
// Reg-staged A and B (issue loads early, ds_write late). XOR swizzle:
// LDS 16B slot ^= (row&7) on write AND read.
__global__ __launch_bounds__(256, 2)
void gemm1_kernel(const __bf16* __restrict__ xb, const float* __restrict__ W1,
                  const float* __restrict__ Up, const int* __restrict__ btok,
                  const float* __restrict__ bw, const int* __restrict__ offs,
                  __bf16* __restrict__ hbuf) {
    const int e = blockIdx.z;
    const int seg0 = offs[e];
    const int ne = offs[e + 1] - seg0;
    const int m0 = blockIdx.y * 128;
    if (m0 >= ne) return;
    const int n0 = blockIdx.x * 64;

    __shared__ __align__(16) __bf16 sA[2][128 * 64];   // 32 KB
    __shared__ __align__(16) __bf16 sB1[2][64 * 64];   // 16 KB
    __shared__ __align__(16) __bf16 sB2[2][64 * 64];   // 16 KB -> 64 KB total

    const int tid = threadIdx.x;

    // A staging: thread -> rows (tid>>3)+32i (i<4), 16B slot (tid&7)
    const int ar = tid >> 3;
    const int as = tid & 7;
    const __bf16* aSrc[4];
    int awoff[4];
#pragma unroll
    for (int i = 0; i < 4; ++i) {
        const int row = ar + 32 * i;
        int rr = m0 + row;
        if (rr >= ne) rr = ne - 1;                     // clamp; rows discarded in epilogue
        aSrc[i] = xb + (size_t)btok[seg0 + rr] * kH + as * 8;
        awoff[i] = row * 64 + ((as ^ (row & 7)) << 3); // swizzled LDS write offset
    }

    // B staging: thread -> rows (tid>>3)+32i (i<2), fp32 cols (tid&7)*8..+7
    const int bcf = as * 8;
    const float* b1p = W1 + ((size_t)e * kI + n0 + ar) * kH + bcf;
    const float* b2p = Up + ((size_t)e * kI + n0 + ar) * kH + bcf;
    int bwoff[2];
#pragma unroll
    for (int i = 0; i < 2; ++i) {
        const int row = ar + 32 * i;
        bwoff[i] = row * 64 + ((as ^ (row & 7)) << 3);
    }

    const int wid = tid >> 6, lane = tid & 63;
    const int wm = (wid >> 1) * 64, wn = (wid & 1) * 32;
    const int lr = lane & 15;
    const int lkq = lane >> 4;                          // 16B slot within K-half

    floatx4 acc1[4][2], acc2[4][2];
#pragma unroll
    for (int i = 0; i < 4; ++i)
#pragma unroll
        for (int j = 0; j < 2; ++j) { acc1[i][j] = (floatx4)0.f; acc2[i][j] = (floatx4)0.f; }

    // prologue: stage tile 0 into buf 0
    {
        uint4 apf[4];
#pragma unroll
        for (int i = 0; i < 4; ++i) apf[i] = *(const uint4*)(aSrc[i]);
#pragma unroll
        for (int i = 0; i < 4; ++i) *(uint4*)(&sA[0][awoff[i]]) = apf[i];
#pragma unroll
        for (int i = 0; i < 2; ++i) {
            float4 v0 = *(const float4*)(b1p + (size_t)(32 * i) * kH);
            float4 v1 = *(const float4*)(b1p + (size_t)(32 * i) * kH + 4);
            float4 v2 = *(const float4*)(b2p + (size_t)(32 * i) * kH);
            float4 v3 = *(const float4*)(b2p + (size_t)(32 * i) * kH + 4);
            *(uint4*)(&sB1[0][bwoff[i]]) = pack8(v0, v1);
            *(uint4*)(&sB2[0][bwoff[i]]) = pack8(v2, v3);
        }
    }
    __syncthreads();

    int cb = 0;
    constexpr int nK = kH / 64;                         // 32
    for (int t = 0; t < nK; ++t) {
        const int nb = cb ^ 1;
        const bool hn = (t + 1) < nK;
        uint4 apf[4];
        float4 p0[2], p1[2], p2[2], p3[2];
        if (hn) {                                       // issue next-tile loads EARLY
            const int kn = (t + 1) * 64;
#pragma unroll
            for (int i = 0; i < 4; ++i) apf[i] = *(const uint4*)(aSrc[i] + kn);
#pragma unroll
            for (int i = 0; i < 2; ++i) {
                p0[i] = *(const float4*)(b1p + (size_t)(32 * i) * kH + kn);
                p1[i] = *(const float4*)(b1p + (size_t)(32 * i) * kH + kn + 4);
                p2[i] = *(const float4*)(b2p + (size_t)(32 * i) * kH + kn);
                p3[i] = *(const float4*)(b2p + (size_t)(32 * i) * kH + kn + 4);
            }
        }
        // MFMA phase on current buffer (HBM latency of the loads hides under this)
#pragma unroll
        for (int ks = 0; ks < 2; ++ks) {
            bf16x8 af[4], bq1[2], bq2[2];
#pragma unroll
            for (int i = 0; i < 4; ++i) {
                const int row = wm + i * 16 + lr;
                af[i] = *(const bf16x8*)(&sA[cb][row * 64 + (((ks * 4 + lkq) ^ (row & 7)) << 3)]);
            }
#pragma unroll
            for (int j = 0; j < 2; ++j) {
                const int row = wn + j * 16 + lr;
                const int so = row * 64 + (((ks * 4 + lkq) ^ (row & 7)) << 3);
                bq1[j] = *(const bf16x8*)(&sB1[cb][so]);
                bq2[j] = *(const bf16x8*)(&sB2[cb][so]);
            }
#pragma unroll
            for (int i = 0; i < 4; ++i)
#pragma unroll
                for (int j = 0; j < 2; ++j) {
                    acc1[i][j] = __builtin_amdgcn_mfma_f32_16x16x32_bf16(af[i], bq1[j], acc1[i][j], 0, 0, 0);
                    acc2[i][j] = __builtin_amdgcn_mfma_f32_16x16x32_bf16(af[i], bq2[j], acc2[i][j], 0, 0, 0);
                }
        }
        if (hn) {                                       // write LATE into next buffer
#pragma unroll
            for (int i = 0; i < 4; ++i) *(uint4*)(&sA[nb][awoff[i]]) = apf[i];
#pragma unroll
            for (int i = 0; i < 2; ++i) {
                *(uint4*)(&sB1[nb][bwoff[i]]) = pack8(p0[i], p1[i]);
                *(uint4*)(&sB2[nb][bwoff[i]]) = pack8(p2[i], p3[i]);
            }
        }
        __syncthreads();
        cb = nb;
    }

    // epilogue: silu(a1)*a2 * route_w -> bf16 h
    const int q4 = (lane >> 4) * 4;
#pragma unroll
    for (int i = 0; i < 4; ++i) {
#pragma unroll
        for (int r = 0; r < 4; ++r) {
            const int row = wm + i * 16 + q4 + r;
            if (m0 + row < ne) {
                const float wrt = bw[seg0 + m0 + row];
                __bf16* hp = hbuf + (size_t)(seg0 + m0 + row) * kI + n0 + wn + (lane & 15);
#pragma unroll
                for (int j = 0; j < 2; ++j) {
                    float a = acc1[i][j][r];
                    float b = acc2[i][j][r];
                    float s = a / (1.f + __expf(-a));
                    hp[j * 16] = f2bf(s * b * wrt);
                }
            }
        }
    }
}

// ---------------- grouped GEMM2: out[tok] += h@W2^T ----------------
__global__ __launch_bounds__(256, 2)
void gemm2_kernel(const __bf16* __restrict__ hbuf, const float* __restrict__ W2,
                  const int* __restrict__ btok, const int* __restrict__ offs,
                  float* __restrict__ out) {
    const int e = blockIdx.z;
    const int seg0 = offs[e];
    const int ne = offs[e + 1] - seg0;
    const int m0 = blockIdx.y * 128;
    if (m0 >= ne) return;
    const int n0 = blockIdx.x * 64;

    __shared__ __align__(16) __bf16 sA[2][128 * 64];   // 32 KB
    __shared__ __align__(16) __bf16 sB[2][64 * 64];    // 16 KB -> 48 KB total

    const int tid = threadIdx.x;
    const int ar = tid >> 3;
    const int as = tid & 7;

    const __bf16* aSrc[4];
    int awoff[4];
#pragma unroll
    for (int i = 0; i < 4; ++i) {
        const int row = ar + 32 * i;
        int rr = m0 + row;
        if (rr >= ne) rr = ne - 1;
        aSrc[i] = hbuf + (size_t)(seg0 + rr) * kI + as * 8;
        awoff[i] = row * 64 + ((as ^ (row & 7)) << 3);
    }

    const int bcf = as * 8;
    const float* bp = W2 + ((size_t)e * kH + n0 + ar) * kI + bcf;
    int bwoff[2];
#pragma unroll
    for (int i = 0; i < 2; ++i) {
        const int row = ar + 32 * i;
        bwoff[i] = row * 64 + ((as ^ (row & 7)) << 3);
    }

    const int wid = tid >> 6, lane = tid & 63;
    const int wm = (wid >> 1) * 64, wn = (wid & 1) * 32;
    const int lr = lane & 15;
    const int lkq = lane >> 4;

    floatx4 acc[4][2];
#pragma unroll
    for (int i = 0; i < 4; ++i)
#pragma unroll
        for (int j = 0; j < 2; ++j) acc[i][j] = (floatx4)0.f;

    // prologue
    {
        uint4 apf[4];
#pragma unroll
        for (int i = 0; i < 4; ++i) apf[i] = *(const uint4*)(aSrc[i]);
#pragma unroll
        for (int i = 0; i < 4; ++i) *(uint4*)(&sA[0][awoff[i]]) = apf[i];
#pragma unroll
        for (int i = 0; i < 2; ++i) {
            float4 v0 = *(const float4*)(bp + (size_t)(32 * i) * kI);
            float4 v1 = *(const float4*)(bp + (size_t)(32 * i) * kI + 4);
            *(uint4*)(&sB[0][bwoff[i]]) = pack8(v0, v1);
        }
    }
    __syncthreads();

    int cb = 0;
    constexpr int nK = kI / 64;                         // 22
    for (int t = 0; t < nK; ++t) {
        const int nb = cb ^ 1;
        const bool hn = (t + 1) < nK;
        uint4 apf[4];
        float4 p0[2], p1[2];
        if (hn) {
            const int kn = (t + 1) * 64;
#pragma unroll
            for (int i = 0; i < 4; ++i) apf[i] = *(const uint4*)(aSrc[i] + kn);
#pragma unroll
            for (int i = 0; i < 2; ++i) {
                p0[i] = *(const float4*)(bp + (size_t)(32 * i) * kI + kn);
                p1[i] = *(const float4*)(bp + (size_t)(32 * i) * kI + kn + 4);
            }
        }
#pragma unroll
        for (int ks = 0; ks < 2; ++ks) {
            bf16x8 af[4], bq[2];
#pragma unroll
            for (int i = 0; i < 4; ++i) {
                const int row = wm + i * 16 + lr;
                af[i] = *(const bf16x8*)(&sA[cb][row * 64 + (((ks * 4 + lkq) ^ (row & 7)) << 3)]);
            }
#pragma unroll
            for (int j = 0; j < 2; ++j) {
                const int row = wn + j * 16 + lr;
                bq[j] = *(const bf16x8*)(&sB[cb][row * 64 + (((ks * 4 + lkq) ^ (row & 7)) << 3)]);
            }
#pragma unroll
            for (int i = 0; i < 4; ++i)
#pragma unroll
                for (int j = 0; j < 2; ++j)
                    acc[i][j] = __builtin_amdgcn_mfma_f32_16x16x32_bf16(af[i], bq[j], acc[i][j], 0, 0, 0);
        }
        if (hn) {
#pragma unroll
            for (int i = 0; i < 4; ++i) *(uint4*)(&sA[nb][awoff[i]]) = apf[i];
#pragma unroll
            for (int i = 0; i < 2; ++i)
                *(uint4*)(&sB[nb][bwoff[i]]) = pack8(p0[i], p1[i]);
        }
        __syncthreads();
        cb = nb;
    }

    const int q4 = (lane >> 4) * 4;
#pragma unroll
    for (int i = 0; i < 4; ++i) {
#pragma unroll
        for (int r = 0; r < 4; ++r) {
            const int row = wm + i * 16 + q4 + r;
            if (m0 + row < ne) {
                const int tok = btok[seg0 + m0 + row];
                float* op = out + (size_t)tok * kH + n0 + wn + (lane & 15);
#pragma unroll
                for (int j = 0; j < 2; ++j)
                    atomicAdd(op + j * 16, acc[i][j][r]);
            }
        }
    }
}

extern "C" void kernel_launch(void* const* d_in, const int* in_sizes, int n_in,
                              void* d_out, int out_size, void* d_ws, size_t ws_size,
                              hipStream_t stream) {
    const float* x  = (const float*)d_in[0];
    const float* gw = (const float*)d_in[1];
    const float* W1 = (const float*)d_in[2];
    const float* Up = (const float*)d_in[3];
    const float* W2 = (const float*)d_in[4];
    float* out = (float*)d_out;

    // workspace layout (~80 MB)
    char* ws = (char*)d_ws;
    size_t o = 0;
    __bf16* xb   = (__bf16*)(ws + o); o += (size_t)kT * kH * 2;          // 33.5 MB
    __bf16* hbuf = (__bf16*)(ws + o); o += (size_t)(2 * kT) * kI * 2;    // 46.1 MB
    int*   t_ids = (int*)(ws + o);    o += (size_t)(2 * kT) * 4;
    float* t_w   = (float*)(ws + o);  o += (size_t)(2 * kT) * 4;
    int*   btok  = (int*)(ws + o);    o += (size_t)(2 * kT) * 4;
    float* bw    = (float*)(ws + o);  o += (size_t)(2 * kT) * 4;
    int*   counts = (int*)(ws + o);   o += 64;
    int*   offs   = (int*)(ws + o);   o += 128;
    int*   fill   = (int*)(ws + o);   o += 64;

    hipMemsetAsync(out, 0, (size_t)kT * kH * sizeof(float), stream);
    hipMemsetAsync(counts, 0, kE * sizeof(int), stream);

    cvt_x_kernel<<<(kT * kH / 8) / 256, 256, 0, stream>>>(x, xb);
    gate_kernel<<<kT / 4, 256, 0, stream>>>(x, gw, t_ids, t_w, counts);
    scan_kernel<<<1, 64, 0, stream>>>(counts, offs, fill);
    scatter_kernel<<<(kT + 255) / 256, 256, 0, stream>>>(t_ids, t_w, fill, btok, bw);

    dim3 g1(kI / 64, 64, kE);
    gemm1_kernel<<<g1, 256, 0, stream>>>(xb, W1, Up, btok, bw, offs, hbuf);
    dim3 g2(kH / 64, 64, kE);
    gemm2_kernel<<<g2, 256, 0, stream>>>(hbuf, W2, btok, offs, out);
}